// Round 12
// baseline (1085.411 us; speedup 1.0000x reference)
//
#include <hip/hip_runtime.h>
#include <math.h>

// Problem constants
// B=256, T=512, E=768, Hd=50, 4*Hd=200, H=100, K=11, START=9, STOP=10, NEG=-1000
// M = B*T = 131072

typedef _Float16 half8 __attribute__((ext_vector_type(8)));
typedef _Float16 half4 __attribute__((ext_vector_type(4)));
typedef float f32x4 __attribute__((ext_vector_type(4)));

// ---------------------------------------------------------------------------
// Kernel 1: xw[M][400] = emb[M][768] @ concat(W_ih_f, W_ih_b)^T
// Split-precision fp16 MFMA (hi+lo, 3 products) => ~fp32 accuracy at f16 rate.
// ---------------------------------------------------------------------------
__global__ __launch_bounds__(256) void k_gemm_split(
    const float* __restrict__ emb,
    const float* __restrict__ Wf,     // [200][768]
    const float* __restrict__ Wb,     // [200][768]
    float* __restrict__ xw)           // [M][400]
{
    __shared__ _Float16 Ah[128 * 64];
    __shared__ _Float16 Al[128 * 64];
    __shared__ _Float16 Bh[80 * 64];
    __shared__ _Float16 Bl[80 * 64];

    const int bid = blockIdx.x;
    const int wg  = (bid & 7) * 640 + (bid >> 3);
    const int mt  = wg / 5;
    const int nb  = wg - mt * 5;
    const size_t m0 = (size_t)mt * 128;
    const int n0 = nb * 80;

    const int tid  = threadIdx.x;
    const int lane = tid & 63;
    const int w    = tid >> 6;        // wave 0..3, rows w*32..+31
    const int grp  = lane >> 4;       // 0..3
    const int r16  = lane & 15;

    f32x4 acc[2][5];
    #pragma unroll
    for (int m = 0; m < 2; ++m)
        #pragma unroll
        for (int n = 0; n < 5; ++n) acc[m][n] = (f32x4){0.f, 0.f, 0.f, 0.f};

    for (int kt = 0; kt < 12; ++kt) {
        const int k0 = kt * 64;
        __syncthreads();

        #pragma unroll
        for (int j = 0; j < 8; ++j) {
            const int flat = j * 256 + tid;      // 0..2047 float4 slots
            const int row  = flat >> 4;          // 0..127
            const int q    = flat & 15;          // float4 col
            const float4 v = *(const float4*)(emb + (m0 + row) * 768 + k0 + q * 4);
            half4 hv, lv;
            hv[0] = (_Float16)v.x; lv[0] = (_Float16)(v.x - (float)hv[0]);
            hv[1] = (_Float16)v.y; lv[1] = (_Float16)(v.y - (float)hv[1]);
            hv[2] = (_Float16)v.z; lv[2] = (_Float16)(v.z - (float)hv[2]);
            hv[3] = (_Float16)v.w; lv[3] = (_Float16)(v.w - (float)hv[3]);
            const int s    = (q >> 1) ^ (row & 7);
            const int addr = row * 64 + s * 8 + (q & 1) * 4;
            *(half4*)(Ah + addr) = hv;
            *(half4*)(Al + addr) = lv;
        }
        #pragma unroll
        for (int j = 0; j < 5; ++j) {
            const int flat = j * 256 + tid;      // 0..1279
            const int row  = flat >> 4;          // 0..79
            const int q    = flat & 15;
            const int n    = n0 + row;
            const float* src = (n < 200) ? (Wf + (size_t)n * 768)
                                         : (Wb + (size_t)(n - 200) * 768);
            const float4 v = *(const float4*)(src + k0 + q * 4);
            half4 hv, lv;
            hv[0] = (_Float16)v.x; lv[0] = (_Float16)(v.x - (float)hv[0]);
            hv[1] = (_Float16)v.y; lv[1] = (_Float16)(v.y - (float)hv[1]);
            hv[2] = (_Float16)v.z; lv[2] = (_Float16)(v.z - (float)hv[2]);
            hv[3] = (_Float16)v.w; lv[3] = (_Float16)(v.w - (float)hv[3]);
            const int s    = (q >> 1) ^ (row & 7);
            const int addr = row * 64 + s * 8 + (q & 1) * 4;
            *(half4*)(Bh + addr) = hv;
            *(half4*)(Bl + addr) = lv;
        }
        __syncthreads();

        #pragma unroll
        for (int ks = 0; ks < 2; ++ks) {
            const int kslot = ks * 4 + grp;
            half8 ah[2], al[2], bh[5], bl[5];
            #pragma unroll
            for (int m = 0; m < 2; ++m) {
                const int row = w * 32 + m * 16 + r16;
                const int ad  = row * 64 + (kslot ^ (row & 7)) * 8;
                ah[m] = *(half8*)(Ah + ad);
                al[m] = *(half8*)(Al + ad);
            }
            #pragma unroll
            for (int n = 0; n < 5; ++n) {
                const int row = n * 16 + r16;
                const int ad  = row * 64 + (kslot ^ (row & 7)) * 8;
                bh[n] = *(half8*)(Bh + ad);
                bl[n] = *(half8*)(Bl + ad);
            }
            #pragma unroll
            for (int m = 0; m < 2; ++m)
                #pragma unroll
                for (int n = 0; n < 5; ++n) {
                    acc[m][n] = __builtin_amdgcn_mfma_f32_16x16x32_f16(ah[m], bh[n], acc[m][n], 0, 0, 0);
                    acc[m][n] = __builtin_amdgcn_mfma_f32_16x16x32_f16(ah[m], bl[n], acc[m][n], 0, 0, 0);
                    acc[m][n] = __builtin_amdgcn_mfma_f32_16x16x32_f16(al[m], bh[n], acc[m][n], 0, 0, 0);
                }
        }
    }

    #pragma unroll
    for (int m = 0; m < 2; ++m) {
        #pragma unroll
        for (int n = 0; n < 5; ++n) {
            #pragma unroll
            for (int i = 0; i < 4; ++i) {
                const size_t row = m0 + w * 32 + m * 16 + (lane >> 4) * 4 + i;
                const int    col = n0 + n * 16 + (lane & 15);
                xw[row * 400 + col] = acc[m][n][i];
            }
        }
    }
}

// ---------------------------------------------------------------------------
// Kernel 2: bidirectional LSTM recurrence — TWO same-direction chains per
// block. The 6-variant post-mortem showed per-step cost = per-thread weight
// streaming (~13 x 16B L2 loads/thread/step), invariant to weight home.
// Dedupe: thread g's w[52] serves BOTH chains (one set of SSA loads, CSE'd
// by the compiler even when sunk) -> per-CU weight requests HALVE (256
// blocks = 1/CU vs R1's 2/CU). Per-chain FMA order is bit-identical to R1.
// Nonlin: chain A on lanes 0..49 (wave 0), chain B on lanes 128..177
// (wave 2) — parallel SIMDs, private c state each.
// ---------------------------------------------------------------------------
__global__ __launch_bounds__(256) void k_lstm(
    const float* __restrict__ xw,     // [131072][400] (fwd gates 0..199, bwd 200..399)
    const float* __restrict__ Whh_f,  // [200][50]
    const float* __restrict__ Whh_b,
    const float* __restrict__ bf_,    // [200]
    const float* __restrict__ bb_,
    float* __restrict__ hout)         // [131072][100] (fwd 0..49, bwd 50..99)
{
    const int pair = blockIdx.x & 127;    // batch pair 0..127
    const int dir  = blockIdx.x >> 7;     // 0 fwd, 1 bwd
    const int bA   = pair * 2;
    const int bB   = bA + 1;
    const int g    = threadIdx.x;

    __shared__ float h_sA[52], h_sB[52];
    __shared__ float g_sA[200], g_sB[200];

    const float* Whh  = dir ? Whh_b : Whh_f;
    const float* bias = dir ? bb_ : bf_;

    float w[52];
    float bg = 0.f;
    if (g < 200) {
        #pragma unroll
        for (int j = 0; j < 50; ++j) w[j] = Whh[g * 50 + j];
        w[50] = 0.f; w[51] = 0.f;
        bg = bias[g];
    } else {
        #pragma unroll
        for (int j = 0; j < 52; ++j) w[j] = 0.f;
    }

    if (g < 52) { h_sA[g] = 0.f; h_sB[g] = 0.f; }
    float c = 0.f;     // cA on lanes 0..49; cB on lanes 128..177
    __syncthreads();

    const size_t baseA = (size_t)bA * 512;
    const size_t baseB = (size_t)bB * 512;
    const int col = dir * 200 + ((g < 200) ? g : 0);

    float xvA = 0.f, xvB = 0.f;
    {
        const int t0 = dir ? 511 : 0;
        if (g < 200) {
            xvA = xw[(baseA + t0) * 400 + col];
            xvB = xw[(baseB + t0) * 400 + col];
        }
    }

    for (int it = 0; it < 512; ++it) {
        const int t = dir ? (511 - it) : it;
        const float xcA = xvA, xcB = xvB;
        if (it + 1 < 512) {
            const int tn = dir ? (510 - it) : (it + 1);
            if (g < 200) {
                xvA = xw[(baseA + tn) * 400 + col];
                xvB = xw[(baseB + tn) * 400 + col];
            }
        }

        // dots: one weight load stream serves both chains; per-chain op
        // order identical to R1 (sequential fmaf over 52 terms)
        float sumA = bg + xcA;
        float sumB = bg + xcB;
        const float4* h4A = (const float4*)h_sA;
        const float4* h4B = (const float4*)h_sB;
        #pragma unroll
        for (int q = 0; q < 13; ++q) {
            const float4 hvA = h4A[q];
            const float4 hvB = h4B[q];
            sumA = fmaf(w[q * 4 + 0], hvA.x, sumA);
            sumA = fmaf(w[q * 4 + 1], hvA.y, sumA);
            sumA = fmaf(w[q * 4 + 2], hvA.z, sumA);
            sumA = fmaf(w[q * 4 + 3], hvA.w, sumA);
            sumB = fmaf(w[q * 4 + 0], hvB.x, sumB);
            sumB = fmaf(w[q * 4 + 1], hvB.y, sumB);
            sumB = fmaf(w[q * 4 + 2], hvB.z, sumB);
            sumB = fmaf(w[q * 4 + 3], hvB.w, sumB);
        }
        if (g < 200) { g_sA[g] = sumA; g_sB[g] = sumB; }
        __syncthreads();

        if (g < 50) {
            // chain A, unit g
            const float gi = g_sA[g];
            const float gf = g_sA[g + 50];
            const float gg = g_sA[g + 100];
            const float go = g_sA[g + 150];
            const float si = 1.f / (1.f + expf(-gi));
            const float sf = 1.f / (1.f + expf(-gf));
            const float so = 1.f / (1.f + expf(-go));
            c = sf * c + si * tanhf(gg);
            const float h = so * tanhf(c);
            hout[(baseA + t) * 100 + dir * 50 + g] = h;
            h_sA[g] = h;
        } else if (g >= 128 && g < 178) {
            // chain B, unit g-128
            const int u = g - 128;
            const float gi = g_sB[u];
            const float gf = g_sB[u + 50];
            const float gg = g_sB[u + 100];
            const float go = g_sB[u + 150];
            const float si = 1.f / (1.f + expf(-gi));
            const float sf = 1.f / (1.f + expf(-gf));
            const float so = 1.f / (1.f + expf(-go));
            c = sf * c + si * tanhf(gg);
            const float h = so * tanhf(c);
            hout[(baseB + t) * 100 + dir * 50 + u] = h;
            h_sB[u] = h;
        }
        __syncthreads();
    }
}

// ---------------------------------------------------------------------------
// Kernel 3: emissions logits[bt][11] = hout[bt][100] @ Wout^T + bout
// ---------------------------------------------------------------------------
__global__ __launch_bounds__(256) void k_emis(
    const float* __restrict__ hout,   // [131072][100]
    const float* __restrict__ Wout,   // [11][100]
    const float* __restrict__ bout,   // [11]
    float* __restrict__ logits)       // [131072][11]
{
    __shared__ float Wl[1104];
    __shared__ float bl[11];
    const int tid = threadIdx.x;
    for (int i = tid; i < 1100; i += 256) Wl[i] = Wout[i];
    if (tid < 11) bl[tid] = bout[tid];
    __syncthreads();

    const size_t bt = (size_t)blockIdx.x * 256 + tid;
    const float4* h4 = (const float4*)(hout + bt * 100);
    float acc[11];
    #pragma unroll
    for (int k = 0; k < 11; ++k) acc[k] = bl[k];
    #pragma unroll
    for (int q = 0; q < 25; ++q) {
        float4 v = h4[q];
        #pragma unroll
        for (int k = 0; k < 11; ++k) {
            const float4 wv = *(const float4*)&Wl[k * 100 + q * 4];
            acc[k] = fmaf(v.x, wv.x, fmaf(v.y, wv.y, fmaf(v.z, wv.z, fmaf(v.w, wv.w, acc[k]))));
        }
    }
    #pragma unroll
    for (int k = 0; k < 11; ++k) logits[bt * 11 + k] = acc[k];
}

// ---------------------------------------------------------------------------
// Kernel 4: CRF forward scan + logsumexp score + fused Viterbi backtrace.
// Register-resident scan (R11, passed absmax 0.0): na = f[c] + M +
// log(sum_p exp(al[p]-M)*E[c][p]) with E precomputed; argmax first-max
// ascending over al[p]+trc[p] (f[c] cancels). Zero LDS in the scan loop.
// ---------------------------------------------------------------------------
__global__ __launch_bounds__(64, 1) void k_crf(
    const float* __restrict__ logits,   // [131072][11]
    const int* __restrict__ mask,       // [256][512]
    const float* __restrict__ trans,    // [11][11]
    float* __restrict__ scores,         // [256]
    float* __restrict__ paths)          // [256][512] (as float)
{
    const int b = blockIdx.x;
    const int lane = threadIdx.x;
    const int lanec = (lane < 11) ? lane : 10;   // clamp for safe addressing

    __shared__ unsigned char bp[512][12];

    float trc[11], E[11];
    #pragma unroll
    for (int p = 0; p < 11; ++p) {
        trc[p] = trans[p * 11 + lanec];
        E[p]   = expf(trc[p]);                   // once; amortized over 512 steps
    }

    float al_c = (lane == 9) ? 0.f : -1000.f;    // alpha[c] lives in lane c (<11)

    const size_t lbase = (size_t)b * 512;

    float f_cur = logits[lbase * 11 + lanec];
    int   m_cur = mask[lbase];

    for (int t = 0; t < 512; ++t) {
        float f_next = 0.f; int m_next = 1;
        if (t + 1 < 512) {
            f_next = logits[(lbase + t + 1) * 11 + lanec];
            m_next = mask[lbase + t + 1];
        }

        float a[11];
        #pragma unroll
        for (int p = 0; p < 11; ++p) a[p] = __shfl(al_c, p);

        float vmax = a[0] + trc[0]; int amax = 0;
        #pragma unroll
        for (int p = 1; p < 11; ++p) {
            const float vp = a[p] + trc[p];
            if (vp > vmax) { vmax = vp; amax = p; }
        }

        const float m01 = fmaxf(a[0], a[1]),  m23 = fmaxf(a[2], a[3]);
        const float m45 = fmaxf(a[4], a[5]),  m67 = fmaxf(a[6], a[7]);
        const float m89 = fmaxf(a[8], a[9]);
        const float mA  = fmaxf(fmaxf(m01, m23), fmaxf(m45, m67));
        const float M   = fmaxf(mA, fmaxf(m89, a[10]));

        float e[11];
        #pragma unroll
        for (int p = 0; p < 11; ++p) e[p] = __expf(a[p] - M) * E[p];
        const float s01 = e[0] + e[1], s23 = e[2] + e[3];
        const float s45 = e[4] + e[5], s67 = e[6] + e[7];
        const float s89 = e[8] + e[9];
        const float S = ((s01 + s23) + (s45 + s67)) + (s89 + e[10]);

        const float na = f_cur + (M + __logf(S));

        if (lane < 11) {
            if (m_cur > 0) {
                al_c = na;
                bp[t][lane] = (unsigned char)amax;
            } else {
                bp[t][lane] = (unsigned char)lane;
            }
        }
        f_cur = f_next;
        m_cur = m_next;
    }

    float fin = (lane < 11) ? (al_c + trans[lane * 11 + 10]) : -1e30f;
    float m = fin;
    int am = (lane < 11) ? lane : 1000;
    #pragma unroll
    for (int off = 8; off >= 1; off >>= 1) {
        float om = __shfl_xor(m, off, 16);
        int   oa = __shfl_xor(am, off, 16);
        if (om > m || (om == m && oa < am)) { m = om; am = oa; }
    }
    float s = (lane < 11) ? expf(fin - m) : 0.f;
    #pragma unroll
    for (int off = 8; off >= 1; off >>= 1) s += __shfl_xor(s, off, 16);

    if (lane == 0) {
        scores[b] = m + logf(s);
        int cur = am;
        paths[lbase + 511] = (float)cur;
        for (int t = 511; t >= 1; --t) {
            cur = bp[t][cur];
            paths[lbase + t - 1] = (float)cur;
        }
    }
}

// ---------------------------------------------------------------------------
extern "C" void kernel_launch(void* const* d_in, const int* in_sizes, int n_in,
                              void* d_out, int out_size, void* d_ws, size_t ws_size,
                              hipStream_t stream) {
    const float* emb   = (const float*)d_in[0];
    const int*   imask = (const int*)d_in[1];
    const float* Wihf  = (const float*)d_in[2];
    const float* Whhf  = (const float*)d_in[3];
    const float* bf_   = (const float*)d_in[4];
    const float* Wihb  = (const float*)d_in[5];
    const float* Whhb  = (const float*)d_in[6];
    const float* bb_   = (const float*)d_in[7];
    const float* Wout  = (const float*)d_in[8];
    const float* bout  = (const float*)d_in[9];
    const float* trans = (const float*)d_in[10];

    float* out = (float*)d_out;
    float* ws  = (float*)d_ws;
    float* xw     = ws;                          // 131072*400 f32 = 209.7 MB
    float* hout   = xw + (size_t)131072 * 400;   // 131072*100 f32 = 52.4 MB
    float* logits = hout + (size_t)131072 * 100; // 131072*11  f32 = 5.8 MB

    k_gemm_split<<<5120, 256, 0, stream>>>(emb, Wihf, Wihb, xw);
    k_lstm<<<256, 256, 0, stream>>>(xw, Whhf, Whhb, bf_, bb_, hout);
    k_emis<<<512, 256, 0, stream>>>(hout, Wout, bout, logits);
    k_crf<<<256, 64, 0, stream>>>(logits, imask, trans, out, out + 256);
}

// Round 13
// 979.325 us; speedup vs baseline: 1.1083x; 1.1083x over previous
//
#include <hip/hip_runtime.h>
#include <math.h>

// Problem constants
// B=256, T=512, E=768, Hd=50, 4*Hd=200, H=100, K=11, START=9, STOP=10, NEG=-1000
// M = B*T = 131072

typedef _Float16 half8 __attribute__((ext_vector_type(8)));
typedef _Float16 half4 __attribute__((ext_vector_type(4)));
typedef float f32x4 __attribute__((ext_vector_type(4)));

// Non-draining workgroup barrier (learn_hip m201 pattern): LDS visibility
// only — no vmcnt drain, so prefetch loads issued before the barrier stay
// in flight across it. sched_barrier(0) pins ds ops on both sides.
#define LBAR() do {                                   \
    __builtin_amdgcn_sched_barrier(0);                \
    asm volatile("s_waitcnt lgkmcnt(0)");             \
    __builtin_amdgcn_s_barrier();                     \
    __builtin_amdgcn_sched_barrier(0);                \
} while (0)

// ---------------------------------------------------------------------------
// Kernel 0: one-time hi/lo fp16 split of concat(W_ih_f, W_ih_b) [400][768].
// Same per-element ops as the in-loop split it replaces -> identical bits.
// ---------------------------------------------------------------------------
__global__ __launch_bounds__(256) void k_bsplit(
    const float* __restrict__ Wf,     // [200][768]
    const float* __restrict__ Wb,     // [200][768]
    _Float16* __restrict__ Bh,        // [400*768]
    _Float16* __restrict__ Bl)
{
    const int i = blockIdx.x * 256 + threadIdx.x;   // 0..307199
    if (i < 400 * 768) {
        const int n = i / 768;
        const int k = i - n * 768;
        const float v = (n < 200) ? Wf[n * 768 + k] : Wb[(n - 200) * 768 + k];
        const _Float16 hi = (_Float16)v;
        Bh[i] = hi;
        Bl[i] = (_Float16)(v - (float)hi);
    }
}

// ---------------------------------------------------------------------------
// Kernel 1: xw[M][400] = emb[M][768] @ concat(W_ih_f, W_ih_b)^T
// Split-precision fp16 MFMA (hi+lo, 3 products) => ~fp32 accuracy at f16 rate.
// K-loop barriers are non-draining (LBAR): the 13 prefetch loads/thread
// issued before the MFMA phase are no longer force-drained at the loop-top
// barrier — they only need to land by their convert/store use one phase
// later. B arrives pre-split (k_bsplit) -> B staging is pure half4 moves.
// ---------------------------------------------------------------------------
__global__ __launch_bounds__(256) void k_gemm_split(
    const float* __restrict__ emb,
    const _Float16* __restrict__ Bhg, // [400][768] pre-split hi
    const _Float16* __restrict__ Blg, // [400][768] pre-split lo
    float* __restrict__ xw)           // [M][400]
{
    __shared__ _Float16 Ah[128 * 64];
    __shared__ _Float16 Al[128 * 64];
    __shared__ _Float16 Bh[80 * 64];
    __shared__ _Float16 Bl[80 * 64];

    const int bid = blockIdx.x;
    const int wg  = (bid & 7) * 640 + (bid >> 3);
    const int mt  = wg / 5;
    const int nb  = wg - mt * 5;
    const size_t m0 = (size_t)mt * 128;
    const int n0 = nb * 80;

    const int tid  = threadIdx.x;
    const int lane = tid & 63;
    const int w    = tid >> 6;        // wave 0..3, rows w*32..+31
    const int grp  = lane >> 4;       // 0..3
    const int r16  = lane & 15;

    // staging coordinates
    const int arow = tid >> 1;              // A: 0..127
    const int aq0  = (tid & 1) * 8;         // A: float4 slots aq0..aq0+7 (handled as 8/thread? no)
    // A: 2048 float4 slots over 256 threads = 8 each (j loop), same as before
    const int brow = tid >> 4;              // unused placeholder

    f32x4 acc[2][5];
    #pragma unroll
    for (int m = 0; m < 2; ++m)
        #pragma unroll
        for (int n = 0; n < 5; ++n) acc[m][n] = (f32x4){0.f, 0.f, 0.f, 0.f};

    // prefetch kt=0
    float4 apf[8];
    half4  bph[5], bpl[5];
    #pragma unroll
    for (int j = 0; j < 8; ++j) {
        const int flat = j * 256 + tid;
        const int row  = flat >> 4;
        const int q    = flat & 15;
        apf[j] = *(const float4*)(emb + (m0 + row) * 768 + q * 4);
    }
    #pragma unroll
    for (int j = 0; j < 5; ++j) {
        const int flat = j * 256 + tid;      // 0..1279
        const int row  = flat >> 4;          // 0..79
        const int q    = flat & 15;
        const size_t src = (size_t)(n0 + row) * 768 + q * 4;
        bph[j] = *(const half4*)(Bhg + src);
        bpl[j] = *(const half4*)(Blg + src);
    }

    for (int kt = 0; kt < 12; ++kt) {
        LBAR();   // all waves done reading LDS from previous iteration

        // ---- stage A: convert prefetched f32 -> hi/lo fp16, swizzled ----
        #pragma unroll
        for (int j = 0; j < 8; ++j) {
            const int flat = j * 256 + tid;
            const int row  = flat >> 4;
            const int q    = flat & 15;
            const float4 v = apf[j];
            half4 hv, lv;
            hv[0] = (_Float16)v.x; lv[0] = (_Float16)(v.x - (float)hv[0]);
            hv[1] = (_Float16)v.y; lv[1] = (_Float16)(v.y - (float)hv[1]);
            hv[2] = (_Float16)v.z; lv[2] = (_Float16)(v.z - (float)hv[2]);
            hv[3] = (_Float16)v.w; lv[3] = (_Float16)(v.w - (float)hv[3]);
            const int s    = (q >> 1) ^ (row & 7);
            const int addr = row * 64 + s * 8 + (q & 1) * 4;
            *(half4*)(Ah + addr) = hv;
            *(half4*)(Al + addr) = lv;
        }
        // ---- stage B: pre-split halves, straight to swizzled LDS ----
        #pragma unroll
        for (int j = 0; j < 5; ++j) {
            const int flat = j * 256 + tid;
            const int row  = flat >> 4;
            const int q    = flat & 15;
            const int s    = (q >> 1) ^ (row & 7);
            const int addr = row * 64 + s * 8 + (q & 1) * 4;
            *(half4*)(Bh + addr) = bph[j];
            *(half4*)(Bl + addr) = bpl[j];
        }

        // ---- issue prefetch for kt+1 (consumed after the NEXT LBAR) ----
        if (kt + 1 < 12) {
            const int k0 = (kt + 1) * 64;
            #pragma unroll
            for (int j = 0; j < 8; ++j) {
                const int flat = j * 256 + tid;
                const int row  = flat >> 4;
                const int q    = flat & 15;
                apf[j] = *(const float4*)(emb + (m0 + row) * 768 + k0 + q * 4);
            }
            #pragma unroll
            for (int j = 0; j < 5; ++j) {
                const int flat = j * 256 + tid;
                const int row  = flat >> 4;
                const int q    = flat & 15;
                const size_t src = (size_t)(n0 + row) * 768 + k0 + q * 4;
                bph[j] = *(const half4*)(Bhg + src);
                bpl[j] = *(const half4*)(Blg + src);
            }
        }

        LBAR();   // staged tile visible to all waves; prefetch stays in flight

        // ---- compute: 2 k-steps of 32 ----
        #pragma unroll
        for (int ks = 0; ks < 2; ++ks) {
            const int kslot = ks * 4 + grp;
            half8 ah[2], al[2], bh[5], bl[5];
            #pragma unroll
            for (int m = 0; m < 2; ++m) {
                const int row = w * 32 + m * 16 + r16;
                const int ad  = row * 64 + (kslot ^ (row & 7)) * 8;
                ah[m] = *(half8*)(Ah + ad);
                al[m] = *(half8*)(Al + ad);
            }
            #pragma unroll
            for (int n = 0; n < 5; ++n) {
                const int row = n * 16 + r16;
                const int ad  = row * 64 + (kslot ^ (row & 7)) * 8;
                bh[n] = *(half8*)(Bh + ad);
                bl[n] = *(half8*)(Bl + ad);
            }
            #pragma unroll
            for (int m = 0; m < 2; ++m)
                #pragma unroll
                for (int n = 0; n < 5; ++n) {
                    acc[m][n] = __builtin_amdgcn_mfma_f32_16x16x32_f16(ah[m], bh[n], acc[m][n], 0, 0, 0);
                    acc[m][n] = __builtin_amdgcn_mfma_f32_16x16x32_f16(ah[m], bl[n], acc[m][n], 0, 0, 0);
                    acc[m][n] = __builtin_amdgcn_mfma_f32_16x16x32_f16(al[m], bh[n], acc[m][n], 0, 0, 0);
                }
        }
    }

    // ---- epilogue: C/D layout col=lane&15, row=(lane>>4)*4+i ----
    #pragma unroll
    for (int m = 0; m < 2; ++m) {
        #pragma unroll
        for (int n = 0; n < 5; ++n) {
            #pragma unroll
            for (int i = 0; i < 4; ++i) {
                const size_t row = m0 + w * 32 + m * 16 + (lane >> 4) * 4 + i;
                const int    col = n0 + n * 16 + (lane & 15);
                xw[row * 400 + col] = acc[m][n][i];
            }
        }
    }
}

// ---------------------------------------------------------------------------
// Kernel 2: bidirectional LSTM recurrence. One block per (batch, dir).
// R1 structure verbatim — floor established over 8 variants (457 us):
// 2 chains/CU is the hard parallelism cap (512 chains / 256 CUs), so weight
// dedup always trades away the TLP that hides the serial phases. LOCKED.
// ---------------------------------------------------------------------------
__global__ __launch_bounds__(256) void k_lstm(
    const float* __restrict__ xw,     // [131072][400] (fwd gates 0..199, bwd 200..399)
    const float* __restrict__ Whh_f,  // [200][50]
    const float* __restrict__ Whh_b,
    const float* __restrict__ bf_,    // [200]
    const float* __restrict__ bb_,
    float* __restrict__ hout)         // [131072][100] (fwd 0..49, bwd 50..99)
{
    const int b   = blockIdx.x >> 1;
    const int dir = blockIdx.x & 1;
    const int g   = threadIdx.x;

    __shared__ float h_s[52];
    __shared__ float g_s[200];

    const float* Whh  = dir ? Whh_b : Whh_f;
    const float* bias = dir ? bb_ : bf_;

    float w[52];
    float bg = 0.f;
    if (g < 200) {
        #pragma unroll
        for (int j = 0; j < 50; ++j) w[j] = Whh[g * 50 + j];
        w[50] = 0.f; w[51] = 0.f;
        bg = bias[g];
    } else {
        #pragma unroll
        for (int j = 0; j < 52; ++j) w[j] = 0.f;
    }

    if (g < 52) h_s[g] = 0.f;
    float c = 0.f;
    __syncthreads();

    const size_t base = (size_t)b * 512;

    float xv = 0.f;
    {
        int t0 = dir ? 511 : 0;
        if (g < 200) xv = xw[(base + t0) * 400 + dir * 200 + g];
    }

    for (int it = 0; it < 512; ++it) {
        const int t = dir ? (511 - it) : it;
        float xcur = xv;
        if (it + 1 < 512) {
            int tn = dir ? (510 - it) : (it + 1);
            if (g < 200) xv = xw[(base + tn) * 400 + dir * 200 + g];
        }

        float sum = bg + xcur;
        const float4* h4 = (const float4*)h_s;
        #pragma unroll
        for (int q = 0; q < 13; ++q) {
            float4 hv = h4[q];
            sum = fmaf(w[q * 4 + 0], hv.x, sum);
            sum = fmaf(w[q * 4 + 1], hv.y, sum);
            sum = fmaf(w[q * 4 + 2], hv.z, sum);
            sum = fmaf(w[q * 4 + 3], hv.w, sum);
        }
        if (g < 200) g_s[g] = sum;
        __syncthreads();

        if (g < 50) {
            float gi = g_s[g];
            float gf = g_s[g + 50];
            float gg = g_s[g + 100];
            float go = g_s[g + 150];
            float si = 1.f / (1.f + expf(-gi));
            float sf = 1.f / (1.f + expf(-gf));
            float so = 1.f / (1.f + expf(-go));
            c = sf * c + si * tanhf(gg);
            float h = so * tanhf(c);
            hout[(base + t) * 100 + dir * 50 + g] = h;
            h_s[g] = h;
        }
        __syncthreads();
    }
}

// ---------------------------------------------------------------------------
// Kernel 3: emissions logits[bt][11] = hout[bt][100] @ Wout^T + bout
// ---------------------------------------------------------------------------
__global__ __launch_bounds__(256) void k_emis(
    const float* __restrict__ hout,   // [131072][100]
    const float* __restrict__ Wout,   // [11][100]
    const float* __restrict__ bout,   // [11]
    float* __restrict__ logits)       // [131072][11]
{
    __shared__ float Wl[1104];
    __shared__ float bl[11];
    const int tid = threadIdx.x;
    for (int i = tid; i < 1100; i += 256) Wl[i] = Wout[i];
    if (tid < 11) bl[tid] = bout[tid];
    __syncthreads();

    const size_t bt = (size_t)blockIdx.x * 256 + tid;
    const float4* h4 = (const float4*)(hout + bt * 100);
    float acc[11];
    #pragma unroll
    for (int k = 0; k < 11; ++k) acc[k] = bl[k];
    #pragma unroll
    for (int q = 0; q < 25; ++q) {
        float4 v = h4[q];
        #pragma unroll
        for (int k = 0; k < 11; ++k) {
            const float4 wv = *(const float4*)&Wl[k * 100 + q * 4];
            acc[k] = fmaf(v.x, wv.x, fmaf(v.y, wv.y, fmaf(v.z, wv.z, fmaf(v.w, wv.w, acc[k]))));
        }
    }
    #pragma unroll
    for (int k = 0; k < 11; ++k) logits[bt * 11 + k] = acc[k];
}

// ---------------------------------------------------------------------------
// Kernel 4: CRF forward scan + logsumexp score + fused Viterbi backtrace.
// Register-resident scan (R11, passed absmax 0.0): na = f[c] + M +
// log(sum_p exp(al[p]-M)*E[c][p]) with E precomputed; argmax first-max
// ascending over al[p]+trc[p] (f[c] cancels). Zero LDS in the scan loop.
// ---------------------------------------------------------------------------
__global__ __launch_bounds__(64, 1) void k_crf(
    const float* __restrict__ logits,   // [131072][11]
    const int* __restrict__ mask,       // [256][512]
    const float* __restrict__ trans,    // [11][11]
    float* __restrict__ scores,         // [256]
    float* __restrict__ paths)          // [256][512] (as float)
{
    const int b = blockIdx.x;
    const int lane = threadIdx.x;
    const int lanec = (lane < 11) ? lane : 10;   // clamp for safe addressing

    __shared__ unsigned char bp[512][12];

    float trc[11], E[11];
    #pragma unroll
    for (int p = 0; p < 11; ++p) {
        trc[p] = trans[p * 11 + lanec];
        E[p]   = expf(trc[p]);                   // once; amortized over 512 steps
    }

    float al_c = (lane == 9) ? 0.f : -1000.f;    // alpha[c] lives in lane c (<11)

    const size_t lbase = (size_t)b * 512;

    float f_cur = logits[lbase * 11 + lanec];
    int   m_cur = mask[lbase];

    for (int t = 0; t < 512; ++t) {
        float f_next = 0.f; int m_next = 1;
        if (t + 1 < 512) {
            f_next = logits[(lbase + t + 1) * 11 + lanec];
            m_next = mask[lbase + t + 1];
        }

        float a[11];
        #pragma unroll
        for (int p = 0; p < 11; ++p) a[p] = __shfl(al_c, p);

        float vmax = a[0] + trc[0]; int amax = 0;
        #pragma unroll
        for (int p = 1; p < 11; ++p) {
            const float vp = a[p] + trc[p];
            if (vp > vmax) { vmax = vp; amax = p; }
        }

        const float m01 = fmaxf(a[0], a[1]),  m23 = fmaxf(a[2], a[3]);
        const float m45 = fmaxf(a[4], a[5]),  m67 = fmaxf(a[6], a[7]);
        const float m89 = fmaxf(a[8], a[9]);
        const float mA  = fmaxf(fmaxf(m01, m23), fmaxf(m45, m67));
        const float M   = fmaxf(mA, fmaxf(m89, a[10]));

        float e[11];
        #pragma unroll
        for (int p = 0; p < 11; ++p) e[p] = __expf(a[p] - M) * E[p];
        const float s01 = e[0] + e[1], s23 = e[2] + e[3];
        const float s45 = e[4] + e[5], s67 = e[6] + e[7];
        const float s89 = e[8] + e[9];
        const float S = ((s01 + s23) + (s45 + s67)) + (s89 + e[10]);

        const float na = f_cur + (M + __logf(S));

        if (lane < 11) {
            if (m_cur > 0) {
                al_c = na;
                bp[t][lane] = (unsigned char)amax;
            } else {
                bp[t][lane] = (unsigned char)lane;
            }
        }
        f_cur = f_next;
        m_cur = m_next;
    }

    float fin = (lane < 11) ? (al_c + trans[lane * 11 + 10]) : -1e30f;
    float m = fin;
    int am = (lane < 11) ? lane : 1000;
    #pragma unroll
    for (int off = 8; off >= 1; off >>= 1) {
        float om = __shfl_xor(m, off, 16);
        int   oa = __shfl_xor(am, off, 16);
        if (om > m || (om == m && oa < am)) { m = om; am = oa; }
    }
    float s = (lane < 11) ? expf(fin - m) : 0.f;
    #pragma unroll
    for (int off = 8; off >= 1; off >>= 1) s += __shfl_xor(s, off, 16);

    if (lane == 0) {
        scores[b] = m + logf(s);
        int cur = am;
        paths[lbase + 511] = (float)cur;
        for (int t = 511; t >= 1; --t) {
            cur = bp[t][cur];
            paths[lbase + t - 1] = (float)cur;
        }
    }
}

// ---------------------------------------------------------------------------
extern "C" void kernel_launch(void* const* d_in, const int* in_sizes, int n_in,
                              void* d_out, int out_size, void* d_ws, size_t ws_size,
                              hipStream_t stream) {
    const float* emb   = (const float*)d_in[0];
    const int*   imask = (const int*)d_in[1];
    const float* Wihf  = (const float*)d_in[2];
    const float* Whhf  = (const float*)d_in[3];
    const float* bf_   = (const float*)d_in[4];
    const float* Wihb  = (const float*)d_in[5];
    const float* Whhb  = (const float*)d_in[6];
    const float* bb_   = (const float*)d_in[7];
    const float* Wout  = (const float*)d_in[8];
    const float* bout  = (const float*)d_in[9];
    const float* trans = (const float*)d_in[10];

    float* out = (float*)d_out;
    float* ws  = (float*)d_ws;
    float* xw     = ws;                          // 131072*400 f32 = 209.7 MB
    float* hout   = xw + (size_t)131072 * 400;   // 131072*100 f32 = 52.4 MB
    float* logits = hout + (size_t)131072 * 100; // 131072*11  f32 = 5.8 MB

    // Bh/Bl (614 KB each) live in the hout region: consumed by k_gemm_split,
    // overwritten afterwards by k_lstm. Zero extra workspace.
    _Float16* Bh = (_Float16*)hout;
    _Float16* Bl = Bh + (size_t)400 * 768;

    k_bsplit<<<1200, 256, 0, stream>>>(Wihf, Wihb, Bh, Bl);
    k_gemm_split<<<5120, 256, 0, stream>>>(emb, Bh, Bl, xw);
    k_lstm<<<512, 256, 0, stream>>>(xw, Whhf, Whhb, bf_, bb_, hout);
    k_emis<<<512, 256, 0, stream>>>(hout, Wout, bout, logits);
    k_crf<<<256, 64, 0, stream>>>(logits, imask, trans, out, out + 256);
}